// Round 1
// baseline (591.373 us; speedup 1.0000x reference)
//
#include <hip/hip_runtime.h>
#include <stdint.h>

#define D_MODEL 1024
#define SEQ     2048
#define BATCH   4
#define NHEADS  16
#define HDIM    64
#define NBH     (BATCH*NHEADS)   // 64
#define MROWS   (BATCH*SEQ)      // 8192

typedef _Float16 half_t;
typedef __attribute__((ext_vector_type(8))) _Float16 half8;
typedef __attribute__((ext_vector_type(4))) _Float16 half4;
typedef __attribute__((ext_vector_type(4))) float f32x4;

// ---------------- fp32 -> fp16 conversion ----------------
__global__ __launch_bounds__(256) void k_cvt(const float* __restrict__ src,
                                             half_t* __restrict__ dst, int n4) {
  int i = blockIdx.x * 256 + threadIdx.x;
  if (i < n4) {
    float4 v = reinterpret_cast<const float4*>(src)[i];
    half4 o = {(_Float16)v.x, (_Float16)v.y, (_Float16)v.z, (_Float16)v.w};
    *reinterpret_cast<half4*>(dst + (size_t)i * 4) = o;
  }
}

// ---------------- GEMM1: qkv = x @ w_qkv^T + b, scatter to Q/K/VT ----------------
#define BM 128
#define BN 128
#define BK 32

__global__ __launch_bounds__(256) void k_gemm_qkv(
    const half_t* __restrict__ A,    // [8192][1024]
    const half_t* __restrict__ W,    // [3072][1024] (row = out col)
    const float*  __restrict__ bias, // [3072]
    half_t* __restrict__ Qo,         // [64][2048][64]
    half_t* __restrict__ Ko,         // [64][2048][64]
    half_t* __restrict__ VTo)        // [64][64][2048]
{
  constexpr int K = D_MODEL;
  __shared__ __align__(16) half_t As[BM * BK];
  __shared__ __align__(16) half_t Bs[BN * BK];
  const int tid  = threadIdx.x;
  const int wave = tid >> 6, lane = tid & 63;
  const int wr = wave >> 1, wc = wave & 1;
  const int lg = lane >> 4, lq = lane & 15;
  const int m0 = blockIdx.x * BM, n0 = blockIdx.y * BN;

  f32x4 acc[4][4] = {};

  const int srow = tid >> 2;        // 0..63
  const int scol = (tid & 3) * 8;   // 0,8,16,24

  const half_t* Ag = A + (size_t)(m0 + srow) * K + scol;
  const half_t* Wg = W + (size_t)(n0 + srow) * K + scol;

  for (int k0 = 0; k0 < K; k0 += BK) {
    __syncthreads();
    *(half8*)(&As[srow * BK + scol])        = *(const half8*)(Ag + k0);
    *(half8*)(&As[(srow + 64) * BK + scol]) = *(const half8*)(Ag + (size_t)64 * K + k0);
    *(half8*)(&Bs[srow * BK + scol])        = *(const half8*)(Wg + k0);
    *(half8*)(&Bs[(srow + 64) * BK + scol]) = *(const half8*)(Wg + (size_t)64 * K + k0);
    __syncthreads();
    half8 af[4], bf[4];
#pragma unroll
    for (int mt = 0; mt < 4; ++mt)
      af[mt] = *(const half8*)(&As[(wr * 64 + mt * 16 + lq) * BK + lg * 8]);
#pragma unroll
    for (int nt = 0; nt < 4; ++nt)
      bf[nt] = *(const half8*)(&Bs[(wc * 64 + nt * 16 + lq) * BK + lg * 8]);
#pragma unroll
    for (int mt = 0; mt < 4; ++mt)
#pragma unroll
      for (int nt = 0; nt < 4; ++nt)
        acc[mt][nt] = __builtin_amdgcn_mfma_f32_16x16x32_f16(af[mt], bf[nt], acc[mt][nt], 0, 0, 0);
  }

  const int sec   = n0 >> 10;      // 0=q 1=k 2=v (BN=128 stays in one section)
  const int csec0 = n0 & 1023;
#pragma unroll
  for (int mt = 0; mt < 4; ++mt) {
#pragma unroll
    for (int nt = 0; nt < 4; ++nt) {
      const int n  = n0 + wc * 64 + nt * 16 + lq;
      const float bv = bias[n];
      const int c = csec0 + wc * 64 + nt * 16 + lq;
      const int h = c >> 6, d = c & 63;
#pragma unroll
      for (int r = 0; r < 4; ++r) {
        const int m = m0 + wr * 64 + mt * 16 + lg * 4 + r;
        const int b = m >> 11, s = m & 2047;
        const half_t val = (half_t)(acc[mt][nt][r] + bv);
        const int bhh = (b << 4) + h;
        if (sec == 0)      Qo[((size_t)bhh * SEQ + s) * HDIM + d] = val;
        else if (sec == 1) Ko[((size_t)bhh * SEQ + s) * HDIM + d] = val;
        else               VTo[((size_t)bhh * HDIM + d) * SEQ + s] = val;
      }
    }
  }
}

// ---------------- flash attention (causal) ----------------
// grid: (SEQ/64, NBH); block 256 = 4 waves, each wave owns 16 q-rows.
__global__ __launch_bounds__(256) void k_attn(
    const half_t* __restrict__ Q,   // [64][2048][64]
    const half_t* __restrict__ Kt,  // [64][2048][64]
    const half_t* __restrict__ Vt,  // [64][64][2048]  (V transposed)
    half_t* __restrict__ O)         // [8192][1024]
{
  const int qt   = blockIdx.x;      // 0..31
  const int bh   = blockIdx.y;      // 0..63
  const int wave = threadIdx.x >> 6, lane = threadIdx.x & 63;
  const int lg = lane >> 4, lq = lane & 15;

  const half_t* Qh = Q  + (size_t)bh * SEQ * HDIM;
  const half_t* Kh = Kt + (size_t)bh * SEQ * HDIM;
  const half_t* Vh = Vt + (size_t)bh * HDIM * SEQ;

  const int qrow0 = qt * 64 + wave * 16;

  half8 qf[2];
#pragma unroll
  for (int t = 0; t < 2; ++t)
    qf[t] = *(const half8*)(&Qh[(size_t)(qrow0 + lq) * HDIM + t * 32 + lg * 8]);

  f32x4 accO[4] = {};
  float mrun[4], lrun[4];
#pragma unroll
  for (int r = 0; r < 4; ++r) { mrun[r] = -1e30f; lrun[r] = 0.f; }

  // per-wave P staging tile, stride 72 (144B rows: 16B-aligned, ~2-way banks = free)
  __shared__ __align__(16) half_t Plds[4][16 * 72];
  half_t* myP = &Plds[wave][0];

  const float scale = 0.125f;  // 1/sqrt(64)

  for (int kt = 0; kt <= qt; ++kt) {
    // ---- scores: S = Q K^T ----
    f32x4 sc[4] = {};
#pragma unroll
    for (int t = 0; t < 2; ++t) {
#pragma unroll
      for (int st = 0; st < 4; ++st) {
        half8 kf = *(const half8*)(&Kh[(size_t)(kt * 64 + st * 16 + lq) * HDIM + t * 32 + lg * 8]);
        sc[st] = __builtin_amdgcn_mfma_f32_16x16x32_f16(qf[t], kf, sc[st], 0, 0, 0);
      }
    }
    // ---- online softmax ----
    float p[4][4];
    float rmax[4] = {-1e30f, -1e30f, -1e30f, -1e30f};
    const bool diag = (kt == qt);
#pragma unroll
    for (int st = 0; st < 4; ++st) {
      const int kcol = kt * 64 + st * 16 + lq;
#pragma unroll
      for (int r = 0; r < 4; ++r) {
        float v = sc[st][r] * scale;
        if (diag && (kcol > qrow0 + lg * 4 + r)) v = -1e30f;
        p[st][r] = v;
        rmax[r] = fmaxf(rmax[r], v);
      }
    }
#pragma unroll
    for (int r = 0; r < 4; ++r) {
      rmax[r] = fmaxf(rmax[r], __shfl_xor(rmax[r], 1, 64));
      rmax[r] = fmaxf(rmax[r], __shfl_xor(rmax[r], 2, 64));
      rmax[r] = fmaxf(rmax[r], __shfl_xor(rmax[r], 4, 64));
      rmax[r] = fmaxf(rmax[r], __shfl_xor(rmax[r], 8, 64));
    }
    float alpha[4], rsum[4];
#pragma unroll
    for (int r = 0; r < 4; ++r) {
      const float nm = fmaxf(mrun[r], rmax[r]);
      alpha[r] = __expf(mrun[r] - nm);
      mrun[r] = nm;
      rsum[r] = 0.f;
    }
#pragma unroll
    for (int st = 0; st < 4; ++st)
#pragma unroll
      for (int r = 0; r < 4; ++r) {
        const float e = __expf(p[st][r] - mrun[r]);
        p[st][r] = e;
        rsum[r] += e;
      }
#pragma unroll
    for (int r = 0; r < 4; ++r) {
      rsum[r] += __shfl_xor(rsum[r], 1, 64);
      rsum[r] += __shfl_xor(rsum[r], 2, 64);
      rsum[r] += __shfl_xor(rsum[r], 4, 64);
      rsum[r] += __shfl_xor(rsum[r], 8, 64);
      lrun[r] = lrun[r] * alpha[r] + rsum[r];
    }
#pragma unroll
    for (int dst = 0; dst < 4; ++dst)
#pragma unroll
      for (int r = 0; r < 4; ++r)
        accO[dst][r] *= alpha[r];

    // ---- P -> LDS (wave-private, no barrier; DS pipe is in-order per wave) ----
#pragma unroll
    for (int st = 0; st < 4; ++st)
#pragma unroll
      for (int r = 0; r < 4; ++r)
        myP[(lg * 4 + r) * 72 + st * 16 + lq] = (half_t)p[st][r];
    asm volatile("" ::: "memory");  // keep compiler from reordering read before write
    half8 pf[2];
#pragma unroll
    for (int t = 0; t < 2; ++t)
      pf[t] = *(const half8*)(&myP[lq * 72 + t * 32 + lg * 8]);

    // ---- O += P @ V ----
#pragma unroll
    for (int t = 0; t < 2; ++t)
#pragma unroll
      for (int dst = 0; dst < 4; ++dst) {
        half8 vf = *(const half8*)(&Vh[(size_t)(dst * 16 + lq) * SEQ + kt * 64 + t * 32 + lg * 8]);
        accO[dst] = __builtin_amdgcn_mfma_f32_16x16x32_f16(pf[t], vf, accO[dst], 0, 0, 0);
      }
  }

  const int b = bh >> 4, h = bh & 15;
#pragma unroll
  for (int dst = 0; dst < 4; ++dst)
#pragma unroll
    for (int r = 0; r < 4; ++r) {
      const int s = qrow0 + lg * 4 + r;
      O[((size_t)b * SEQ + s) * D_MODEL + h * HDIM + dst * 16 + lq] =
          (half_t)(accO[dst][r] / lrun[r]);
    }
}

// ---------------- GEMM2: out = AO @ w_out^T + b_out (fp32 out) ----------------
__global__ __launch_bounds__(256) void k_gemm_out(
    const half_t* __restrict__ A,    // [8192][1024]
    const half_t* __restrict__ W,    // [1024][1024]
    const float*  __restrict__ bias, // [1024]
    float* __restrict__ C)           // [8192][1024] fp32
{
  constexpr int K = D_MODEL;
  __shared__ __align__(16) half_t As[BM * BK];
  __shared__ __align__(16) half_t Bs[BN * BK];
  const int tid  = threadIdx.x;
  const int wave = tid >> 6, lane = tid & 63;
  const int wr = wave >> 1, wc = wave & 1;
  const int lg = lane >> 4, lq = lane & 15;
  const int m0 = blockIdx.x * BM, n0 = blockIdx.y * BN;

  f32x4 acc[4][4] = {};
  const int srow = tid >> 2;
  const int scol = (tid & 3) * 8;

  const half_t* Ag = A + (size_t)(m0 + srow) * K + scol;
  const half_t* Wg = W + (size_t)(n0 + srow) * K + scol;

  for (int k0 = 0; k0 < K; k0 += BK) {
    __syncthreads();
    *(half8*)(&As[srow * BK + scol])        = *(const half8*)(Ag + k0);
    *(half8*)(&As[(srow + 64) * BK + scol]) = *(const half8*)(Ag + (size_t)64 * K + k0);
    *(half8*)(&Bs[srow * BK + scol])        = *(const half8*)(Wg + k0);
    *(half8*)(&Bs[(srow + 64) * BK + scol]) = *(const half8*)(Wg + (size_t)64 * K + k0);
    __syncthreads();
    half8 af[4], bf[4];
#pragma unroll
    for (int mt = 0; mt < 4; ++mt)
      af[mt] = *(const half8*)(&As[(wr * 64 + mt * 16 + lq) * BK + lg * 8]);
#pragma unroll
    for (int nt = 0; nt < 4; ++nt)
      bf[nt] = *(const half8*)(&Bs[(wc * 64 + nt * 16 + lq) * BK + lg * 8]);
#pragma unroll
    for (int mt = 0; mt < 4; ++mt)
#pragma unroll
      for (int nt = 0; nt < 4; ++nt)
        acc[mt][nt] = __builtin_amdgcn_mfma_f32_16x16x32_f16(af[mt], bf[nt], acc[mt][nt], 0, 0, 0);
  }

#pragma unroll
  for (int mt = 0; mt < 4; ++mt) {
#pragma unroll
    for (int nt = 0; nt < 4; ++nt) {
      const int n = n0 + wc * 64 + nt * 16 + lq;
      const float bv = bias[n];
#pragma unroll
      for (int r = 0; r < 4; ++r) {
        const int m = m0 + wr * 64 + mt * 16 + lg * 4 + r;
        C[(size_t)m * D_MODEL + n] = acc[mt][nt][r] + bv;
      }
    }
  }
}

// ---------------- launch ----------------
extern "C" void kernel_launch(void* const* d_in, const int* in_sizes, int n_in,
                              void* d_out, int out_size, void* d_ws, size_t ws_size,
                              hipStream_t stream) {
  const float* x    = (const float*)d_in[0];
  const float* wqkv = (const float*)d_in[1];
  const float* bqkv = (const float*)d_in[2];
  const float* wout = (const float*)d_in[3];
  const float* bout = (const float*)d_in[4];
  float* out = (float*)d_out;

  char* ws = (char*)d_ws;
  half_t* xb  = (half_t*)ws; ws += (size_t)MROWS * D_MODEL * 2;
  half_t* wqb = (half_t*)ws; ws += (size_t)3 * D_MODEL * D_MODEL * 2;
  half_t* wob = (half_t*)ws; ws += (size_t)D_MODEL * D_MODEL * 2;
  half_t* Qb  = (half_t*)ws; ws += (size_t)NBH * SEQ * HDIM * 2;
  half_t* Kb  = (half_t*)ws; ws += (size_t)NBH * SEQ * HDIM * 2;
  half_t* Vb  = (half_t*)ws; ws += (size_t)NBH * SEQ * HDIM * 2;
  half_t* AO  = (half_t*)ws; ws += (size_t)MROWS * D_MODEL * 2;

  k_cvt<<<MROWS * D_MODEL / 4 / 256, 256, 0, stream>>>(x, xb, MROWS * D_MODEL / 4);
  k_cvt<<<3 * D_MODEL * D_MODEL / 4 / 256, 256, 0, stream>>>(wqkv, wqb, 3 * D_MODEL * D_MODEL / 4);
  k_cvt<<<D_MODEL * D_MODEL / 4 / 256, 256, 0, stream>>>(wout, wob, D_MODEL * D_MODEL / 4);

  k_gemm_qkv<<<dim3(MROWS / BM, 3 * D_MODEL / BN), 256, 0, stream>>>(xb, wqb, bqkv, Qb, Kb, Vb);
  k_attn<<<dim3(SEQ / 64, NBH), 256, 0, stream>>>(Qb, Kb, Vb, AO);
  k_gemm_out<<<dim3(MROWS / BM, D_MODEL / BN), 256, 0, stream>>>(AO, wob, bout, out);
}

// Round 3
// 312.637 us; speedup vs baseline: 1.8916x; 1.8916x over previous
//
#include <hip/hip_runtime.h>
#include <stdint.h>

#define D_MODEL 1024
#define SEQ     2048
#define BATCH   4
#define NHEADS  16
#define HDIM    64
#define NBH     (BATCH*NHEADS)   // 64
#define MROWS   (BATCH*SEQ)      // 8192

typedef _Float16 half_t;
typedef __attribute__((ext_vector_type(8))) _Float16 half8;
typedef __attribute__((ext_vector_type(4))) _Float16 half4;
typedef __attribute__((ext_vector_type(2))) __fp16 fp16x2;
typedef __attribute__((ext_vector_type(4))) float f32x4;
typedef __attribute__((ext_vector_type(16))) float f32x16;

typedef const __attribute__((address_space(1))) void* gas_ptr;
typedef __attribute__((address_space(3))) void* las_ptr;

// async global->LDS, 16B per lane; LDS dest = wave-uniform base + lane*16
__device__ __forceinline__ void g2l16(const half_t* g, half_t* l) {
  __builtin_amdgcn_global_load_lds((gas_ptr)g, (las_ptr)l, 16, 0, 0);
}

__device__ __forceinline__ uint32_t pk16(float a, float b) {
  fp16x2 h = __builtin_amdgcn_cvt_pkrtz(a, b);
  return __builtin_bit_cast(uint32_t, h);
}

// ---------------- fp32 -> fp16 conversion ----------------
__global__ __launch_bounds__(256) void k_cvt(const float* __restrict__ src,
                                             half_t* __restrict__ dst, int n4) {
  int i = blockIdx.x * 256 + threadIdx.x;
  if (i < n4) {
    float4 v = reinterpret_cast<const float4*>(src)[i];
    half4 o = {(_Float16)v.x, (_Float16)v.y, (_Float16)v.z, (_Float16)v.w};
    *reinterpret_cast<half4*>(dst + (size_t)i * 4) = o;
  }
}

// ---------------- GEMM1: qkv = x @ w_qkv^T + b, scatter to Q/K/VT ----------------
#define BM 128
#define BN 128
#define BK 32

__global__ __launch_bounds__(256) void k_gemm_qkv(
    const half_t* __restrict__ A,    // [8192][1024]
    const half_t* __restrict__ W,    // [3072][1024]
    const float*  __restrict__ bias, // [3072]
    half_t* __restrict__ Qo,         // [64][2048][64]
    half_t* __restrict__ Ko,         // [64][2048][64]
    half_t* __restrict__ VTo)        // [64][64][2048]
{
  constexpr int K = D_MODEL;
  __shared__ __align__(16) half_t As[BM * BK];
  __shared__ __align__(16) half_t Bs[BN * BK];
  const int tid  = threadIdx.x;
  const int wave = tid >> 6, lane = tid & 63;
  const int wr = wave >> 1, wc = wave & 1;
  const int lg = lane >> 4, lq = lane & 15;
  const int m0 = blockIdx.x * BM, n0 = blockIdx.y * BN;

  f32x4 acc[4][4] = {};
  const int srow = tid >> 2;        // 0..63
  const int scol = (tid & 3) * 8;

  const half_t* Ag = A + (size_t)(m0 + srow) * K + scol;
  const half_t* Wg = W + (size_t)(n0 + srow) * K + scol;
  half_t* Asw = As + wave * 512;    // wave-uniform LDS base (tid*16 bytes layout)
  half_t* Bsw = Bs + wave * 512;

  for (int k0 = 0; k0 < K; k0 += BK) {
    __syncthreads();
    g2l16(Ag + k0,                    Asw);
    g2l16(Ag + (size_t)64 * K + k0,   Asw + 2048);
    g2l16(Wg + k0,                    Bsw);
    g2l16(Wg + (size_t)64 * K + k0,   Bsw + 2048);
    __syncthreads();
    half8 af[4], bf[4];
#pragma unroll
    for (int mt = 0; mt < 4; ++mt)
      af[mt] = *(const half8*)(&As[(wr * 64 + mt * 16 + lq) * BK + lg * 8]);
#pragma unroll
    for (int nt = 0; nt < 4; ++nt)
      bf[nt] = *(const half8*)(&Bs[(wc * 64 + nt * 16 + lq) * BK + lg * 8]);
#pragma unroll
    for (int mt = 0; mt < 4; ++mt)
#pragma unroll
      for (int nt = 0; nt < 4; ++nt)
        acc[mt][nt] = __builtin_amdgcn_mfma_f32_16x16x32_f16(af[mt], bf[nt], acc[mt][nt], 0, 0, 0);
  }

  const int sec   = n0 >> 10;
  const int csec0 = n0 & 1023;
#pragma unroll
  for (int mt = 0; mt < 4; ++mt) {
#pragma unroll
    for (int nt = 0; nt < 4; ++nt) {
      const int n  = n0 + wc * 64 + nt * 16 + lq;
      const float bv = bias[n];
      const int c = csec0 + wc * 64 + nt * 16 + lq;
      const int h = c >> 6, d = c & 63;
#pragma unroll
      for (int r = 0; r < 4; ++r) {
        const int m = m0 + wr * 64 + mt * 16 + lg * 4 + r;
        const int b = m >> 11, s = m & 2047;
        const half_t val = (half_t)(acc[mt][nt][r] + bv);
        const int bhh = (b << 4) + h;
        if (sec == 0)      Qo[((size_t)bhh * SEQ + s) * HDIM + d] = val;
        else if (sec == 1) Ko[((size_t)bhh * SEQ + s) * HDIM + d] = val;
        else               VTo[((size_t)bhh * HDIM + d) * SEQ + s] = val;
      }
    }
  }
}

// ---------------- flash attention (causal), swapped-QK^T 32x32 MFMA ----------------
// 1D grid of 1024 blocks; block = 4 independent waves, each owns 32 q-rows.
// XCD mapping: heads {h : h%8==x} -> XCD x (assuming round-robin n%8).
__global__ __launch_bounds__(256) void k_attn(
    const half_t* __restrict__ Q,   // [64][2048][64]
    const half_t* __restrict__ Kt,  // [64][2048][64]
    const half_t* __restrict__ Vt,  // [64][64][2048]  (V transposed)
    half_t* __restrict__ O)         // [8192][1024]
{
  const int n   = blockIdx.x;
  const int bh  = (n & 7) + 8 * (n >> 7);   // 0..63
  const int qb  = (n >> 3) & 15;            // 0..15
  const int wave = threadIdx.x >> 6, lane = threadIdx.x & 63;
  const int ql = lane & 31, hi = lane >> 5;

  const half_t* Qh = Q  + (size_t)bh * SEQ * HDIM;
  const half_t* Kh = Kt + (size_t)bh * SEQ * HDIM;
  const half_t* Vh = Vt + (size_t)bh * HDIM * SEQ;

  const int qrow0 = qb * 128 + wave * 32;
  const int qg    = qrow0 + ql;             // this lane's q-row

  // Q fragments (B-operand: col=q=lane&31, k = 8*hi+e at hd-offset 16*kk), prescaled
  half8 qf[4];
  {
    const half_t* Qp = Qh + (size_t)qg * HDIM + hi * 8;
    const _Float16 qs = (_Float16)0.125f;   // 1/sqrt(64), exact in f16
#pragma unroll
    for (int kk = 0; kk < 4; ++kk) {
      half8 t = *(const half8*)(Qp + kk * 16);
      qf[kk] = t * qs;
    }
  }

  f32x16 acc[2] = {};    // O^T tiles: d 0-31, 32-63; col=q, row=d-pattern
  float mrun = -1e30f, lrun = 0.f;
  const int ktd = qrow0 >> 6;

  for (int kt = 0; kt <= ktd; ++kt) {
    // ---- S^T = K · Q^T : A-frag = K rows (row=lane&31, k-slice 8*hi) ----
    f32x16 sc[2] = {};
    const half_t* Kp = Kh + (size_t)(kt * 64 + ql) * HDIM + hi * 8;
#pragma unroll
    for (int kk = 0; kk < 4; ++kk) {
      half8 k0 = *(const half8*)(Kp + kk * 16);
      half8 k1 = *(const half8*)(Kp + 32 * HDIM + kk * 16);
      sc[0] = __builtin_amdgcn_mfma_f32_32x32x16_f16(k0, qf[kk], sc[0], 0, 0, 0);
      sc[1] = __builtin_amdgcn_mfma_f32_32x32x16_f16(k1, qf[kk], sc[1], 0, 0, 0);
    }

    // ---- prefetch V tile (independent of softmax; compiler issues early) ----
    half8 vf[2][4];
    const half_t* Vp = Vh + (size_t)ql * SEQ + kt * 64 + hi * 8;
#pragma unroll
    for (int dt = 0; dt < 2; ++dt)
#pragma unroll
      for (int ks = 0; ks < 4; ++ks)
        vf[dt][ks] = *(const half8*)(Vp + (size_t)dt * 32 * SEQ + ks * 16);

    // ---- causal mask (diag tile only; wave-uniform branch) ----
    if (kt == ktd) {
#pragma unroll
      for (int t = 0; t < 2; ++t)
#pragma unroll
        for (int r = 0; r < 16; ++r) {
          const int kgl = kt * 64 + t * 32 + (r & 3) + 8 * (r >> 2) + 4 * hi;
          sc[t][r] = (kgl > qg) ? -1e30f : sc[t][r];
        }
    }

    // ---- online softmax: per-lane tree + one shfl_xor(32) ----
    float m0 = -1e30f, m1 = -1e30f, m2 = -1e30f, m3 = -1e30f;
#pragma unroll
    for (int t = 0; t < 2; ++t)
#pragma unroll
      for (int r = 0; r < 16; r += 4) {
        m0 = fmaxf(m0, sc[t][r]);     m1 = fmaxf(m1, sc[t][r + 1]);
        m2 = fmaxf(m2, sc[t][r + 2]); m3 = fmaxf(m3, sc[t][r + 3]);
      }
    float mx = fmaxf(fmaxf(m0, m1), fmaxf(m2, m3));
    mx = fmaxf(mx, __shfl_xor(mx, 32, 64));
    const float mnew = fmaxf(mrun, mx);
    const float alpha = __expf(mrun - mnew);
    mrun = mnew;

    float s0 = 0.f, s1 = 0.f, s2 = 0.f, s3 = 0.f;
#pragma unroll
    for (int t = 0; t < 2; ++t)
#pragma unroll
      for (int r = 0; r < 16; r += 4) {
        sc[t][r]     = __expf(sc[t][r]     - mnew); s0 += sc[t][r];
        sc[t][r + 1] = __expf(sc[t][r + 1] - mnew); s1 += sc[t][r + 1];
        sc[t][r + 2] = __expf(sc[t][r + 2] - mnew); s2 += sc[t][r + 2];
        sc[t][r + 3] = __expf(sc[t][r + 3] - mnew); s3 += sc[t][r + 3];
      }
    float lsum = (s0 + s1) + (s2 + s3);
    lsum += __shfl_xor(lsum, 32, 64);
    lrun = lrun * alpha + lsum;
    acc[0] *= alpha;
    acc[1] *= alpha;

    // ---- P^T B-fragments via cvt_pkrtz + shfl_xor(32), then O^T += V^T · P^T ----
#pragma unroll
    for (int ks = 0; ks < 4; ++ks) {
      const int t  = ks >> 1;
      const int r0 = (ks & 1) * 8;
      const uint32_t a0 = pk16(sc[t][r0 + 0], sc[t][r0 + 1]);
      const uint32_t a1 = pk16(sc[t][r0 + 2], sc[t][r0 + 3]);
      const uint32_t a2 = pk16(sc[t][r0 + 4], sc[t][r0 + 5]);
      const uint32_t a3 = pk16(sc[t][r0 + 6], sc[t][r0 + 7]);
      const uint32_t snd0 = hi ? a0 : a2;
      const uint32_t snd1 = hi ? a1 : a3;
      const uint32_t rc0 = (uint32_t)__shfl_xor((int)snd0, 32, 64);
      const uint32_t rc1 = (uint32_t)__shfl_xor((int)snd1, 32, 64);
      union { uint32_t u[4]; half8 h; } fu;
      fu.u[0] = hi ? rc0 : a0;
      fu.u[1] = hi ? rc1 : a1;
      fu.u[2] = hi ? a2  : rc0;
      fu.u[3] = hi ? a3  : rc1;
      acc[0] = __builtin_amdgcn_mfma_f32_32x32x16_f16(vf[0][ks], fu.h, acc[0], 0, 0, 0);
      acc[1] = __builtin_amdgcn_mfma_f32_32x32x16_f16(vf[1][ks], fu.h, acc[1], 0, 0, 0);
    }
  }

  // ---- write O row (q = qg): d = 32*dt + 8*g + 4*hi + j, half4 stores ----
  const int b = bh >> 4, h = bh & 15;
  const float inv = 1.0f / lrun;
  half_t* Orow = O + ((size_t)b * SEQ + qg) * D_MODEL + h * HDIM + hi * 4;
#pragma unroll
  for (int dt = 0; dt < 2; ++dt)
#pragma unroll
    for (int g = 0; g < 4; ++g) {
      half4 o;
#pragma unroll
      for (int j = 0; j < 4; ++j) o[j] = (_Float16)(acc[dt][g * 4 + j] * inv);
      *(half4*)(Orow + dt * 32 + g * 8) = o;
    }
}

// ---------------- GEMM2: out = AO @ w_out^T + b_out (fp32 out) ----------------
__global__ __launch_bounds__(256) void k_gemm_out(
    const half_t* __restrict__ A,
    const half_t* __restrict__ W,
    const float*  __restrict__ bias,
    float* __restrict__ C)
{
  constexpr int K = D_MODEL;
  __shared__ __align__(16) half_t As[BM * BK];
  __shared__ __align__(16) half_t Bs[BN * BK];
  const int tid  = threadIdx.x;
  const int wave = tid >> 6, lane = tid & 63;
  const int wr = wave >> 1, wc = wave & 1;
  const int lg = lane >> 4, lq = lane & 15;
  const int m0 = blockIdx.x * BM, n0 = blockIdx.y * BN;

  f32x4 acc[4][4] = {};
  const int srow = tid >> 2;
  const int scol = (tid & 3) * 8;

  const half_t* Ag = A + (size_t)(m0 + srow) * K + scol;
  const half_t* Wg = W + (size_t)(n0 + srow) * K + scol;
  half_t* Asw = As + wave * 512;
  half_t* Bsw = Bs + wave * 512;

  for (int k0 = 0; k0 < K; k0 += BK) {
    __syncthreads();
    g2l16(Ag + k0,                  Asw);
    g2l16(Ag + (size_t)64 * K + k0, Asw + 2048);
    g2l16(Wg + k0,                  Bsw);
    g2l16(Wg + (size_t)64 * K + k0, Bsw + 2048);
    __syncthreads();
    half8 af[4], bf[4];
#pragma unroll
    for (int mt = 0; mt < 4; ++mt)
      af[mt] = *(const half8*)(&As[(wr * 64 + mt * 16 + lq) * BK + lg * 8]);
#pragma unroll
    for (int nt = 0; nt < 4; ++nt)
      bf[nt] = *(const half8*)(&Bs[(wc * 64 + nt * 16 + lq) * BK + lg * 8]);
#pragma unroll
    for (int mt = 0; mt < 4; ++mt)
#pragma unroll
      for (int nt = 0; nt < 4; ++nt)
        acc[mt][nt] = __builtin_amdgcn_mfma_f32_16x16x32_f16(af[mt], bf[nt], acc[mt][nt], 0, 0, 0);
  }

#pragma unroll
  for (int mt = 0; mt < 4; ++mt) {
#pragma unroll
    for (int nt = 0; nt < 4; ++nt) {
      const int n = n0 + wc * 64 + nt * 16 + lq;
      const float bv = bias[n];
#pragma unroll
      for (int r = 0; r < 4; ++r) {
        const int m = m0 + wr * 64 + mt * 16 + lg * 4 + r;
        C[(size_t)m * D_MODEL + n] = acc[mt][nt][r] + bv;
      }
    }
  }
}

// ---------------- launch ----------------
extern "C" void kernel_launch(void* const* d_in, const int* in_sizes, int n_in,
                              void* d_out, int out_size, void* d_ws, size_t ws_size,
                              hipStream_t stream) {
  const float* x    = (const float*)d_in[0];
  const float* wqkv = (const float*)d_in[1];
  const float* bqkv = (const float*)d_in[2];
  const float* wout = (const float*)d_in[3];
  const float* bout = (const float*)d_in[4];
  float* out = (float*)d_out;

  char* ws = (char*)d_ws;
  half_t* xb  = (half_t*)ws; ws += (size_t)MROWS * D_MODEL * 2;
  half_t* wqb = (half_t*)ws; ws += (size_t)3 * D_MODEL * D_MODEL * 2;
  half_t* wob = (half_t*)ws; ws += (size_t)D_MODEL * D_MODEL * 2;
  half_t* Qb  = (half_t*)ws; ws += (size_t)NBH * SEQ * HDIM * 2;
  half_t* Kb  = (half_t*)ws; ws += (size_t)NBH * SEQ * HDIM * 2;
  half_t* Vb  = (half_t*)ws; ws += (size_t)NBH * SEQ * HDIM * 2;
  half_t* AO  = (half_t*)ws; ws += (size_t)MROWS * D_MODEL * 2;

  k_cvt<<<MROWS * D_MODEL / 4 / 256, 256, 0, stream>>>(x, xb, MROWS * D_MODEL / 4);
  k_cvt<<<3 * D_MODEL * D_MODEL / 4 / 256, 256, 0, stream>>>(wqkv, wqb, 3 * D_MODEL * D_MODEL / 4);
  k_cvt<<<D_MODEL * D_MODEL / 4 / 256, 256, 0, stream>>>(wout, wob, D_MODEL * D_MODEL / 4);

  k_gemm_qkv<<<dim3(MROWS / BM, 3 * D_MODEL / BN), 256, 0, stream>>>(xb, wqb, bqkv, Qb, Kb, Vb);
  k_attn<<<dim3(1024), 256, 0, stream>>>(Qb, Kb, Vb, AO);
  k_gemm_out<<<dim3(MROWS / BM, D_MODEL / BN), 256, 0, stream>>>(AO, wob, bout, out);
}

// Round 4
// 194.813 us; speedup vs baseline: 3.0356x; 1.6048x over previous
//
#include <hip/hip_runtime.h>
#include <stdint.h>

#define D_MODEL 1024
#define SEQ     2048
#define BATCH   4
#define NHEADS  16
#define HDIM    64
#define NBH     (BATCH*NHEADS)   // 64
#define MROWS   (BATCH*SEQ)      // 8192

typedef _Float16 half_t;
typedef __attribute__((ext_vector_type(8))) _Float16 half8;
typedef __attribute__((ext_vector_type(4))) _Float16 half4;
typedef __attribute__((ext_vector_type(2))) __fp16 fp16x2;
typedef __attribute__((ext_vector_type(4))) float f32x4;
typedef __attribute__((ext_vector_type(16))) float f32x16;

typedef const __attribute__((address_space(1))) void* gas_ptr;
typedef __attribute__((address_space(3))) void* las_ptr;

// async global->LDS, 16B per lane; LDS dest = wave-uniform base + lane*16
__device__ __forceinline__ void g2l16(const half_t* g, half_t* l) {
  __builtin_amdgcn_global_load_lds((gas_ptr)g, (las_ptr)l, 16, 0, 0);
}

__device__ __forceinline__ uint32_t pk16(float a, float b) {
  fp16x2 h = __builtin_amdgcn_cvt_pkrtz(a, b);
  return __builtin_bit_cast(uint32_t, h);
}

// ---------------- fp32 -> fp16 conversion ----------------
__global__ __launch_bounds__(256) void k_cvt(const float* __restrict__ src,
                                             half_t* __restrict__ dst, int n4) {
  int i = blockIdx.x * 256 + threadIdx.x;
  if (i < n4) {
    float4 v = reinterpret_cast<const float4*>(src)[i];
    half4 o = {(_Float16)v.x, (_Float16)v.y, (_Float16)v.z, (_Float16)v.w};
    *reinterpret_cast<half4*>(dst + (size_t)i * 4) = o;
  }
}

// ---------------- GEMM1: qkv = x @ w_qkv^T + b, scatter to Q/K/VT ----------------
#define BM 128
#define BN 128
#define BK 32

__global__ __launch_bounds__(256) void k_gemm_qkv(
    const half_t* __restrict__ A,    // [8192][1024]
    const half_t* __restrict__ W,    // [3072][1024]
    const float*  __restrict__ bias, // [3072]
    half_t* __restrict__ Qo,         // [64][2048][64]
    half_t* __restrict__ Ko,         // [64][2048][64]
    half_t* __restrict__ VTo)        // [64][64][2048]
{
  constexpr int K = D_MODEL;
  __shared__ __align__(16) half_t As[BM * BK];
  __shared__ __align__(16) half_t Bs[BN * BK];
  const int tid  = threadIdx.x;
  const int wave = tid >> 6, lane = tid & 63;
  const int wr = wave >> 1, wc = wave & 1;
  const int lg = lane >> 4, lq = lane & 15;
  const int m0 = blockIdx.x * BM, n0 = blockIdx.y * BN;

  f32x4 acc[4][4] = {};
  const int srow = tid >> 2;        // 0..63
  const int scol = (tid & 3) * 8;

  const half_t* Ag = A + (size_t)(m0 + srow) * K + scol;
  const half_t* Wg = W + (size_t)(n0 + srow) * K + scol;
  half_t* Asw = As + wave * 512;    // wave-uniform LDS base (tid*16 bytes layout)
  half_t* Bsw = Bs + wave * 512;

  for (int k0 = 0; k0 < K; k0 += BK) {
    __syncthreads();
    g2l16(Ag + k0,                    Asw);
    g2l16(Ag + (size_t)64 * K + k0,   Asw + 2048);
    g2l16(Wg + k0,                    Bsw);
    g2l16(Wg + (size_t)64 * K + k0,   Bsw + 2048);
    __syncthreads();
    half8 af[4], bf[4];
#pragma unroll
    for (int mt = 0; mt < 4; ++mt)
      af[mt] = *(const half8*)(&As[(wr * 64 + mt * 16 + lq) * BK + lg * 8]);
#pragma unroll
    for (int nt = 0; nt < 4; ++nt)
      bf[nt] = *(const half8*)(&Bs[(wc * 64 + nt * 16 + lq) * BK + lg * 8]);
#pragma unroll
    for (int mt = 0; mt < 4; ++mt)
#pragma unroll
      for (int nt = 0; nt < 4; ++nt)
        acc[mt][nt] = __builtin_amdgcn_mfma_f32_16x16x32_f16(af[mt], bf[nt], acc[mt][nt], 0, 0, 0);
  }

  const int sec   = n0 >> 10;
  const int csec0 = n0 & 1023;
#pragma unroll
  for (int mt = 0; mt < 4; ++mt) {
#pragma unroll
    for (int nt = 0; nt < 4; ++nt) {
      const int n  = n0 + wc * 64 + nt * 16 + lq;
      const float bv = bias[n];
      const int c = csec0 + wc * 64 + nt * 16 + lq;
      const int h = c >> 6, d = c & 63;
#pragma unroll
      for (int r = 0; r < 4; ++r) {
        const int m = m0 + wr * 64 + mt * 16 + lg * 4 + r;
        const int b = m >> 11, s = m & 2047;
        const half_t val = (half_t)(acc[mt][nt][r] + bv);
        const int bhh = (b << 4) + h;
        if (sec == 0)      Qo[((size_t)bhh * SEQ + s) * HDIM + d] = val;
        else if (sec == 1) Ko[((size_t)bhh * SEQ + s) * HDIM + d] = val;
        else               VTo[((size_t)bhh * HDIM + d) * SEQ + s] = val;
      }
    }
  }
}

// ---------------- flash attention (causal), balanced pairs + LDS dbuf staging ----
// grid 512 blocks x 4 waves. Block (head, pg) handles q-tiles {4pg+w} and {63-4pg-w}
// sequentially (32 rows each) -> uniform 34 k-iters per block.
// K/V tiles staged to LDS via global_load_lds, double-buffered, XOR-swizzled
// (linear LDS dest + inverse-swizzled global source + swizzled read).
__global__ __launch_bounds__(256) void k_attn(
    const half_t* __restrict__ Q,   // [64][2048][64]
    const half_t* __restrict__ Kt,  // [64][2048][64]
    const half_t* __restrict__ Vt,  // [64][64][2048]  (V transposed)
    half_t* __restrict__ O)         // [8192][1024]
{
  const int n    = blockIdx.x;                  // 0..511
  const int bh   = (n & 7) * 8 + ((n >> 3) & 7);// head-block: 8 heads per XCD
  const int pg   = n >> 6;                      // 0..7 pair-group
  const int wave = threadIdx.x >> 6, lane = threadIdx.x & 63;
  const int ql   = lane & 31, hi = lane >> 5;
  const int tid  = threadIdx.x;

  __shared__ __align__(16) half_t KS[2][64 * 64];
  __shared__ __align__(16) half_t VS[2][64 * 64];

  const half_t* Qh = Q  + (size_t)bh * SEQ * HDIM;
  const half_t* Kh = Kt + (size_t)bh * SEQ * HDIM;
  const half_t* Vh = Vt + (size_t)bh * HDIM * SEQ;
  const int bb = bh >> 4, hh = bh & 15;

  // staging geometry: thread t covers 16B chunk c16=t&7 of tile-row (i*32 + t>>3);
  // rows r and r+32 share r&7, so the swizzled chunk offset is identical for both halves
  const int sr0  = tid >> 3;                    // 0..31
  const int sc16 = tid & 7;
  const int sw8  = (sc16 ^ (sr0 & 7)) << 3;     // swizzled chunk offset (halfs)
  const size_t ksrc = (size_t)sr0 * HDIM + sw8;
  const size_t vsrc = (size_t)sr0 * SEQ  + sw8;
  const int xw = ql & 7;                        // read-side row XOR key

  for (int ph = 0; ph < 2; ++ph) {
    const int j   = ph ? 63 - (pg * 4 + wave) : pg * 4 + wave;   // q-tile (32 rows)
    const int NT  = ph ? 32 - 2 * pg : 2 * pg + 2;               // block-uniform
    const int ktd = j >> 1;                                      // my last k-tile
    const int qg  = j * 32 + ql;                                 // my q-row

    // Q fragments (B-operand), prescaled by 1/sqrt(64)
    half8 qf[4];
    {
      const half_t* Qp = Qh + (size_t)qg * HDIM + hi * 8;
      const _Float16 qs = (_Float16)0.125f;
#pragma unroll
      for (int kk = 0; kk < 4; ++kk) {
        half8 t = *(const half8*)(Qp + kk * 16);
        qf[kk] = t * qs;
      }
    }

    f32x16 acc[2] = {};
    float mrun = -1e30f, lrun = 0.f;

    // prologue stage of tile 0
    {
      const half_t* kg = Kh + ksrc;
      const half_t* vg = Vh + vsrc;
      g2l16(kg,                     &KS[0][wave * 512]);
      g2l16(kg + 32 * HDIM,         &KS[0][2048 + wave * 512]);
      g2l16(vg,                     &VS[0][wave * 512]);
      g2l16(vg + (size_t)32 * SEQ,  &VS[0][2048 + wave * 512]);
    }
    __syncthreads();

    int cur = 0;
    for (int kt = 0; kt < NT; ++kt) {
      // issue next-tile stage early (lands under this tile's compute)
      if (kt + 1 < NT) {
        const int nb = cur ^ 1;
        const half_t* kg = Kh + (size_t)(kt + 1) * 64 * HDIM + ksrc;
        const half_t* vg = Vh + (kt + 1) * 64 + vsrc;
        g2l16(kg,                     &KS[nb][wave * 512]);
        g2l16(kg + 32 * HDIM,         &KS[nb][2048 + wave * 512]);
        g2l16(vg,                     &VS[nb][wave * 512]);
        g2l16(vg + (size_t)32 * SEQ,  &VS[nb][2048 + wave * 512]);
      }

      if (kt <= ktd) {
        // ---- S^T = K · Q^T from LDS ----
        f32x16 sc[2] = {};
        const half_t* Kl = &KS[cur][0];
#pragma unroll
        for (int kk = 0; kk < 4; ++kk) {
          const int c = ((kk * 2 + hi) ^ xw) << 3;
          half8 k0 = *(const half8*)(Kl + ql * 64 + c);
          half8 k1 = *(const half8*)(Kl + (ql + 32) * 64 + c);
          sc[0] = __builtin_amdgcn_mfma_f32_32x32x16_f16(k0, qf[kk], sc[0], 0, 0, 0);
          sc[1] = __builtin_amdgcn_mfma_f32_32x32x16_f16(k1, qf[kk], sc[1], 0, 0, 0);
        }

        // ---- V fragments from LDS (row d = dt*32+ql shares ql&7 XOR key) ----
        half8 vf[2][4];
        const half_t* Vl = &VS[cur][0];
#pragma unroll
        for (int dt = 0; dt < 2; ++dt)
#pragma unroll
          for (int ks = 0; ks < 4; ++ks) {
            const int c = ((ks * 2 + hi) ^ xw) << 3;
            vf[dt][ks] = *(const half8*)(Vl + (dt * 32 + ql) * 64 + c);
          }

        // ---- causal mask (diag tile only) ----
        if (kt == ktd) {
#pragma unroll
          for (int t = 0; t < 2; ++t)
#pragma unroll
            for (int r = 0; r < 16; ++r) {
              const int kgl = kt * 64 + t * 32 + (r & 3) + 8 * (r >> 2) + 4 * hi;
              sc[t][r] = (kgl > qg) ? -1e30f : sc[t][r];
            }
        }

        // ---- online softmax ----
        float m0 = -1e30f, m1 = -1e30f, m2 = -1e30f, m3 = -1e30f;
#pragma unroll
        for (int t = 0; t < 2; ++t)
#pragma unroll
          for (int r = 0; r < 16; r += 4) {
            m0 = fmaxf(m0, sc[t][r]);     m1 = fmaxf(m1, sc[t][r + 1]);
            m2 = fmaxf(m2, sc[t][r + 2]); m3 = fmaxf(m3, sc[t][r + 3]);
          }
        float mx = fmaxf(fmaxf(m0, m1), fmaxf(m2, m3));
        mx = fmaxf(mx, __shfl_xor(mx, 32, 64));
        const float mnew = fmaxf(mrun, mx);
        const float alpha = __expf(mrun - mnew);
        mrun = mnew;

        float s0 = 0.f, s1 = 0.f, s2 = 0.f, s3 = 0.f;
#pragma unroll
        for (int t = 0; t < 2; ++t)
#pragma unroll
          for (int r = 0; r < 16; r += 4) {
            sc[t][r]     = __expf(sc[t][r]     - mnew); s0 += sc[t][r];
            sc[t][r + 1] = __expf(sc[t][r + 1] - mnew); s1 += sc[t][r + 1];
            sc[t][r + 2] = __expf(sc[t][r + 2] - mnew); s2 += sc[t][r + 2];
            sc[t][r + 3] = __expf(sc[t][r + 3] - mnew); s3 += sc[t][r + 3];
          }
        float lsum = (s0 + s1) + (s2 + s3);
        lsum += __shfl_xor(lsum, 32, 64);
        lrun = lrun * alpha + lsum;
        acc[0] *= alpha;
        acc[1] *= alpha;

        // ---- P^T fragments via cvt_pkrtz + shfl_xor(32); O^T += V^T · P^T ----
#pragma unroll
        for (int ks = 0; ks < 4; ++ks) {
          const int t  = ks >> 1;
          const int r0 = (ks & 1) * 8;
          const uint32_t a0 = pk16(sc[t][r0 + 0], sc[t][r0 + 1]);
          const uint32_t a1 = pk16(sc[t][r0 + 2], sc[t][r0 + 3]);
          const uint32_t a2 = pk16(sc[t][r0 + 4], sc[t][r0 + 5]);
          const uint32_t a3 = pk16(sc[t][r0 + 6], sc[t][r0 + 7]);
          const uint32_t snd0 = hi ? a0 : a2;
          const uint32_t snd1 = hi ? a1 : a3;
          const uint32_t rc0 = (uint32_t)__shfl_xor((int)snd0, 32, 64);
          const uint32_t rc1 = (uint32_t)__shfl_xor((int)snd1, 32, 64);
          union { uint32_t u[4]; half8 h; } fu;
          fu.u[0] = hi ? rc0 : a0;
          fu.u[1] = hi ? rc1 : a1;
          fu.u[2] = hi ? a2  : rc0;
          fu.u[3] = hi ? a3  : rc1;
          acc[0] = __builtin_amdgcn_mfma_f32_32x32x16_f16(vf[0][ks], fu.h, acc[0], 0, 0, 0);
          acc[1] = __builtin_amdgcn_mfma_f32_32x32x16_f16(vf[1][ks], fu.h, acc[1], 0, 0, 0);
        }
      }

      __syncthreads();   // stage of buf[cur^1] landed; all reads of buf[cur] done
      cur ^= 1;
    }

    // ---- write O row qg: d = 32*dt + 8*g + 4*hi + jj ----
    const float inv = 1.0f / lrun;
    half_t* Orow = O + ((size_t)bb * SEQ + qg) * D_MODEL + hh * HDIM + hi * 4;
#pragma unroll
    for (int dt = 0; dt < 2; ++dt)
#pragma unroll
      for (int g = 0; g < 4; ++g) {
        half4 o;
#pragma unroll
        for (int jj = 0; jj < 4; ++jj) o[jj] = (_Float16)(acc[dt][g * 4 + jj] * inv);
        *(half4*)(Orow + dt * 32 + g * 8) = o;
      }
  }
}

// ---------------- GEMM2: out = AO @ w_out^T + b_out (fp32 out) ----------------
__global__ __launch_bounds__(256) void k_gemm_out(
    const half_t* __restrict__ A,
    const half_t* __restrict__ W,
    const float*  __restrict__ bias,
    float* __restrict__ C)
{
  constexpr int K = D_MODEL;
  __shared__ __align__(16) half_t As[BM * BK];
  __shared__ __align__(16) half_t Bs[BN * BK];
  const int tid  = threadIdx.x;
  const int wave = tid >> 6, lane = tid & 63;
  const int wr = wave >> 1, wc = wave & 1;
  const int lg = lane >> 4, lq = lane & 15;
  const int m0 = blockIdx.x * BM, n0 = blockIdx.y * BN;

  f32x4 acc[4][4] = {};
  const int srow = tid >> 2;
  const int scol = (tid & 3) * 8;

  const half_t* Ag = A + (size_t)(m0 + srow) * K + scol;
  const half_t* Wg = W + (size_t)(n0 + srow) * K + scol;
  half_t* Asw = As + wave * 512;
  half_t* Bsw = Bs + wave * 512;

  for (int k0 = 0; k0 < K; k0 += BK) {
    __syncthreads();
    g2l16(Ag + k0,                  Asw);
    g2l16(Ag + (size_t)64 * K + k0, Asw + 2048);
    g2l16(Wg + k0,                  Bsw);
    g2l16(Wg + (size_t)64 * K + k0, Bsw + 2048);
    __syncthreads();
    half8 af[4], bf[4];
#pragma unroll
    for (int mt = 0; mt < 4; ++mt)
      af[mt] = *(const half8*)(&As[(wr * 64 + mt * 16 + lq) * BK + lg * 8]);
#pragma unroll
    for (int nt = 0; nt < 4; ++nt)
      bf[nt] = *(const half8*)(&Bs[(wc * 64 + nt * 16 + lq) * BK + lg * 8]);
#pragma unroll
    for (int mt = 0; mt < 4; ++mt)
#pragma unroll
      for (int nt = 0; nt < 4; ++nt)
        acc[mt][nt] = __builtin_amdgcn_mfma_f32_16x16x32_f16(af[mt], bf[nt], acc[mt][nt], 0, 0, 0);
  }

#pragma unroll
  for (int mt = 0; mt < 4; ++mt) {
#pragma unroll
    for (int nt = 0; nt < 4; ++nt) {
      const int n = n0 + wc * 64 + nt * 16 + lq;
      const float bv = bias[n];
#pragma unroll
      for (int r = 0; r < 4; ++r) {
        const int m = m0 + wr * 64 + mt * 16 + lg * 4 + r;
        C[(size_t)m * D_MODEL + n] = acc[mt][nt][r] + bv;
      }
    }
  }
}

// ---------------- launch ----------------
extern "C" void kernel_launch(void* const* d_in, const int* in_sizes, int n_in,
                              void* d_out, int out_size, void* d_ws, size_t ws_size,
                              hipStream_t stream) {
  const float* x    = (const float*)d_in[0];
  const float* wqkv = (const float*)d_in[1];
  const float* bqkv = (const float*)d_in[2];
  const float* wout = (const float*)d_in[3];
  const float* bout = (const float*)d_in[4];
  float* out = (float*)d_out;

  char* ws = (char*)d_ws;
  half_t* xb  = (half_t*)ws; ws += (size_t)MROWS * D_MODEL * 2;
  half_t* wqb = (half_t*)ws; ws += (size_t)3 * D_MODEL * D_MODEL * 2;
  half_t* wob = (half_t*)ws; ws += (size_t)D_MODEL * D_MODEL * 2;
  half_t* Qb  = (half_t*)ws; ws += (size_t)NBH * SEQ * HDIM * 2;
  half_t* Kb  = (half_t*)ws; ws += (size_t)NBH * SEQ * HDIM * 2;
  half_t* Vb  = (half_t*)ws; ws += (size_t)NBH * SEQ * HDIM * 2;
  half_t* AO  = (half_t*)ws; ws += (size_t)MROWS * D_MODEL * 2;

  k_cvt<<<MROWS * D_MODEL / 4 / 256, 256, 0, stream>>>(x, xb, MROWS * D_MODEL / 4);
  k_cvt<<<3 * D_MODEL * D_MODEL / 4 / 256, 256, 0, stream>>>(wqkv, wqb, 3 * D_MODEL * D_MODEL / 4);
  k_cvt<<<D_MODEL * D_MODEL / 4 / 256, 256, 0, stream>>>(wout, wob, D_MODEL * D_MODEL / 4);

  k_gemm_qkv<<<dim3(MROWS / BM, 3 * D_MODEL / BN), 256, 0, stream>>>(xb, wqb, bqkv, Qb, Kb, Vb);
  k_attn<<<dim3(512), 256, 0, stream>>>(Qb, Kb, Vb, AO);
  k_gemm_out<<<dim3(MROWS / BM, D_MODEL / BN), 256, 0, stream>>>(AO, wob, bout, out);
}

// Round 5
// 194.220 us; speedup vs baseline: 3.0449x; 1.0031x over previous
//
#include <hip/hip_runtime.h>
#include <stdint.h>

#define D_MODEL 1024
#define SEQ     2048
#define BATCH   4
#define NHEADS  16
#define HDIM    64
#define NBH     (BATCH*NHEADS)   // 64
#define MROWS   (BATCH*SEQ)      // 8192

typedef _Float16 half_t;
typedef __attribute__((ext_vector_type(8))) _Float16 half8;
typedef __attribute__((ext_vector_type(4))) _Float16 half4;
typedef __attribute__((ext_vector_type(2))) __fp16 fp16x2;
typedef __attribute__((ext_vector_type(4))) float f32x4;
typedef __attribute__((ext_vector_type(16))) float f32x16;

typedef const __attribute__((address_space(1))) void* gas_ptr;
typedef __attribute__((address_space(3))) void* las_ptr;

// async global->LDS, 16B per lane; LDS dest = wave-uniform base + lane*16
__device__ __forceinline__ void g2l16(const half_t* g, half_t* l) {
  __builtin_amdgcn_global_load_lds((gas_ptr)g, (las_ptr)l, 16, 0, 0);
}

__device__ __forceinline__ uint32_t pk16(float a, float b) {
  fp16x2 h = __builtin_amdgcn_cvt_pkrtz(a, b);
  return __builtin_bit_cast(uint32_t, h);
}

// ---------------- fp32 -> fp16 conversion ----------------
__global__ __launch_bounds__(256) void k_cvt(const float* __restrict__ src,
                                             half_t* __restrict__ dst, int n4) {
  int i = blockIdx.x * 256 + threadIdx.x;
  if (i < n4) {
    float4 v = reinterpret_cast<const float4*>(src)[i];
    half4 o = {(_Float16)v.x, (_Float16)v.y, (_Float16)v.z, (_Float16)v.w};
    *reinterpret_cast<half4*>(dst + (size_t)i * 4) = o;
  }
}

// ---------------- GEMM1: qkv = x @ w_qkv^T + b, scatter to Q/K/VT ----------------
#define BM 128
#define BN 128
#define BK 32

__global__ __launch_bounds__(256) void k_gemm_qkv(
    const half_t* __restrict__ A,    // [8192][1024]
    const half_t* __restrict__ W,    // [3072][1024]
    const float*  __restrict__ bias, // [3072]
    half_t* __restrict__ Qo,         // [64][2048][64]
    half_t* __restrict__ Ko,         // [64][2048][64]
    half_t* __restrict__ VTo)        // [64][64][2048]
{
  constexpr int K = D_MODEL;
  __shared__ __align__(16) half_t As[2][BM * BK];
  __shared__ __align__(16) half_t Bs[2][BN * BK];
  const int tid  = threadIdx.x;
  const int wave = tid >> 6, lane = tid & 63;
  const int wr = wave >> 1, wc = wave & 1;
  const int lg = lane >> 4, lq = lane & 15;
  const int m0 = blockIdx.x * BM, n0 = blockIdx.y * BN;

  f32x4 acc[4][4] = {};
  const int srow = tid >> 2;        // 0..63
  const int scol = (tid & 3) * 8;

  const half_t* Ag = A + (size_t)(m0 + srow) * K + scol;
  const half_t* Wg = W + (size_t)(n0 + srow) * K + scol;
  const int wb = wave * 512;        // wave-uniform LDS offset (tid*16B layout)

  // prologue: stage tile 0 into buf 0
  g2l16(Ag,                  &As[0][wb]);
  g2l16(Ag + (size_t)64 * K, &As[0][wb + 2048]);
  g2l16(Wg,                  &Bs[0][wb]);
  g2l16(Wg + (size_t)64 * K, &Bs[0][wb + 2048]);
  __syncthreads();

  int cur = 0;
  for (int k0 = 0; k0 < K; k0 += BK) {
    // issue next tile's stage into the other buffer (hides under compute)
    if (k0 + BK < K) {
      const int nb = cur ^ 1;
      g2l16(Ag + k0 + BK,                  &As[nb][wb]);
      g2l16(Ag + (size_t)64 * K + k0 + BK, &As[nb][wb + 2048]);
      g2l16(Wg + k0 + BK,                  &Bs[nb][wb]);
      g2l16(Wg + (size_t)64 * K + k0 + BK, &Bs[nb][wb + 2048]);
    }
    half8 af[4], bf[4];
#pragma unroll
    for (int mt = 0; mt < 4; ++mt)
      af[mt] = *(const half8*)(&As[cur][(wr * 64 + mt * 16 + lq) * BK + lg * 8]);
#pragma unroll
    for (int nt = 0; nt < 4; ++nt)
      bf[nt] = *(const half8*)(&Bs[cur][(wc * 64 + nt * 16 + lq) * BK + lg * 8]);
#pragma unroll
    for (int mt = 0; mt < 4; ++mt)
#pragma unroll
      for (int nt = 0; nt < 4; ++nt)
        acc[mt][nt] = __builtin_amdgcn_mfma_f32_16x16x32_f16(af[mt], bf[nt], acc[mt][nt], 0, 0, 0);
    __syncthreads();   // drains stage (vmcnt) + all waves done reading buf[cur]
    cur ^= 1;
  }

  const int sec   = n0 >> 10;
  const int csec0 = n0 & 1023;
#pragma unroll
  for (int mt = 0; mt < 4; ++mt) {
#pragma unroll
    for (int nt = 0; nt < 4; ++nt) {
      const int n  = n0 + wc * 64 + nt * 16 + lq;
      const float bv = bias[n];
      const int c = csec0 + wc * 64 + nt * 16 + lq;
      const int h = c >> 6, d = c & 63;
#pragma unroll
      for (int r = 0; r < 4; ++r) {
        const int m = m0 + wr * 64 + mt * 16 + lg * 4 + r;
        const int b = m >> 11, s = m & 2047;
        const half_t val = (half_t)(acc[mt][nt][r] + bv);
        const int bhh = (b << 4) + h;
        if (sec == 0)      Qo[((size_t)bhh * SEQ + s) * HDIM + d] = val;
        else if (sec == 1) Ko[((size_t)bhh * SEQ + s) * HDIM + d] = val;
        else               VTo[((size_t)bhh * HDIM + d) * SEQ + s] = val;
      }
    }
  }
}

// ---------------- flash attention (causal), balanced pairs + LDS dbuf staging ----
__global__ __launch_bounds__(256) void k_attn(
    const half_t* __restrict__ Q,   // [64][2048][64]
    const half_t* __restrict__ Kt,  // [64][2048][64]
    const half_t* __restrict__ Vt,  // [64][64][2048]  (V transposed)
    half_t* __restrict__ O)         // [8192][1024]
{
  const int n    = blockIdx.x;                  // 0..511
  const int bh   = (n & 7) * 8 + ((n >> 3) & 7);// head-block: 8 heads per XCD
  const int pg   = n >> 6;                      // 0..7 pair-group
  const int wave = threadIdx.x >> 6, lane = threadIdx.x & 63;
  const int ql   = lane & 31, hi = lane >> 5;
  const int tid  = threadIdx.x;

  __shared__ __align__(16) half_t KS[2][64 * 64];
  __shared__ __align__(16) half_t VS[2][64 * 64];

  const half_t* Qh = Q  + (size_t)bh * SEQ * HDIM;
  const half_t* Kh = Kt + (size_t)bh * SEQ * HDIM;
  const half_t* Vh = Vt + (size_t)bh * HDIM * SEQ;
  const int bb = bh >> 4, hh = bh & 15;

  const int sr0  = tid >> 3;                    // 0..31
  const int sc16 = tid & 7;
  const int sw8  = (sc16 ^ (sr0 & 7)) << 3;     // swizzled chunk offset (halfs)
  const size_t ksrc = (size_t)sr0 * HDIM + sw8;
  const size_t vsrc = (size_t)sr0 * SEQ  + sw8;
  const int xw = ql & 7;                        // read-side row XOR key

  for (int ph = 0; ph < 2; ++ph) {
    const int j   = ph ? 63 - (pg * 4 + wave) : pg * 4 + wave;   // q-tile (32 rows)
    const int NT  = ph ? 32 - 2 * pg : 2 * pg + 2;               // block-uniform
    const int ktd = j >> 1;                                      // my last k-tile
    const int qg  = j * 32 + ql;                                 // my q-row

    half8 qf[4];
    {
      const half_t* Qp = Qh + (size_t)qg * HDIM + hi * 8;
      const _Float16 qs = (_Float16)0.125f;
#pragma unroll
      for (int kk = 0; kk < 4; ++kk) {
        half8 t = *(const half8*)(Qp + kk * 16);
        qf[kk] = t * qs;
      }
    }

    f32x16 acc[2] = {};
    float mrun = -1e30f, lrun = 0.f;

    {
      const half_t* kg = Kh + ksrc;
      const half_t* vg = Vh + vsrc;
      g2l16(kg,                     &KS[0][wave * 512]);
      g2l16(kg + 32 * HDIM,         &KS[0][2048 + wave * 512]);
      g2l16(vg,                     &VS[0][wave * 512]);
      g2l16(vg + (size_t)32 * SEQ,  &VS[0][2048 + wave * 512]);
    }
    __syncthreads();

    int cur = 0;
    for (int kt = 0; kt < NT; ++kt) {
      if (kt + 1 < NT) {
        const int nb = cur ^ 1;
        const half_t* kg = Kh + (size_t)(kt + 1) * 64 * HDIM + ksrc;
        const half_t* vg = Vh + (kt + 1) * 64 + vsrc;
        g2l16(kg,                     &KS[nb][wave * 512]);
        g2l16(kg + 32 * HDIM,         &KS[nb][2048 + wave * 512]);
        g2l16(vg,                     &VS[nb][wave * 512]);
        g2l16(vg + (size_t)32 * SEQ,  &VS[nb][2048 + wave * 512]);
      }

      if (kt <= ktd) {
        f32x16 sc[2] = {};
        const half_t* Kl = &KS[cur][0];
#pragma unroll
        for (int kk = 0; kk < 4; ++kk) {
          const int c = ((kk * 2 + hi) ^ xw) << 3;
          half8 k0 = *(const half8*)(Kl + ql * 64 + c);
          half8 k1 = *(const half8*)(Kl + (ql + 32) * 64 + c);
          sc[0] = __builtin_amdgcn_mfma_f32_32x32x16_f16(k0, qf[kk], sc[0], 0, 0, 0);
          sc[1] = __builtin_amdgcn_mfma_f32_32x32x16_f16(k1, qf[kk], sc[1], 0, 0, 0);
        }

        half8 vf[2][4];
        const half_t* Vl = &VS[cur][0];
#pragma unroll
        for (int dt = 0; dt < 2; ++dt)
#pragma unroll
          for (int ks = 0; ks < 4; ++ks) {
            const int c = ((ks * 2 + hi) ^ xw) << 3;
            vf[dt][ks] = *(const half8*)(Vl + (dt * 32 + ql) * 64 + c);
          }

        if (kt == ktd) {
#pragma unroll
          for (int t = 0; t < 2; ++t)
#pragma unroll
            for (int r = 0; r < 16; ++r) {
              const int kgl = kt * 64 + t * 32 + (r & 3) + 8 * (r >> 2) + 4 * hi;
              sc[t][r] = (kgl > qg) ? -1e30f : sc[t][r];
            }
        }

        float m0 = -1e30f, m1 = -1e30f, m2 = -1e30f, m3 = -1e30f;
#pragma unroll
        for (int t = 0; t < 2; ++t)
#pragma unroll
          for (int r = 0; r < 16; r += 4) {
            m0 = fmaxf(m0, sc[t][r]);     m1 = fmaxf(m1, sc[t][r + 1]);
            m2 = fmaxf(m2, sc[t][r + 2]); m3 = fmaxf(m3, sc[t][r + 3]);
          }
        float mx = fmaxf(fmaxf(m0, m1), fmaxf(m2, m3));
        mx = fmaxf(mx, __shfl_xor(mx, 32, 64));
        const float mnew = fmaxf(mrun, mx);
        const float alpha = __expf(mrun - mnew);
        mrun = mnew;

        float s0 = 0.f, s1 = 0.f, s2 = 0.f, s3 = 0.f;
#pragma unroll
        for (int t = 0; t < 2; ++t)
#pragma unroll
          for (int r = 0; r < 16; r += 4) {
            sc[t][r]     = __expf(sc[t][r]     - mnew); s0 += sc[t][r];
            sc[t][r + 1] = __expf(sc[t][r + 1] - mnew); s1 += sc[t][r + 1];
            sc[t][r + 2] = __expf(sc[t][r + 2] - mnew); s2 += sc[t][r + 2];
            sc[t][r + 3] = __expf(sc[t][r + 3] - mnew); s3 += sc[t][r + 3];
          }
        float lsum = (s0 + s1) + (s2 + s3);
        lsum += __shfl_xor(lsum, 32, 64);
        lrun = lrun * alpha + lsum;
        acc[0] *= alpha;
        acc[1] *= alpha;

#pragma unroll
        for (int ks = 0; ks < 4; ++ks) {
          const int t  = ks >> 1;
          const int r0 = (ks & 1) * 8;
          const uint32_t a0 = pk16(sc[t][r0 + 0], sc[t][r0 + 1]);
          const uint32_t a1 = pk16(sc[t][r0 + 2], sc[t][r0 + 3]);
          const uint32_t a2 = pk16(sc[t][r0 + 4], sc[t][r0 + 5]);
          const uint32_t a3 = pk16(sc[t][r0 + 6], sc[t][r0 + 7]);
          const uint32_t snd0 = hi ? a0 : a2;
          const uint32_t snd1 = hi ? a1 : a3;
          const uint32_t rc0 = (uint32_t)__shfl_xor((int)snd0, 32, 64);
          const uint32_t rc1 = (uint32_t)__shfl_xor((int)snd1, 32, 64);
          union { uint32_t u[4]; half8 h; } fu;
          fu.u[0] = hi ? rc0 : a0;
          fu.u[1] = hi ? rc1 : a1;
          fu.u[2] = hi ? a2  : rc0;
          fu.u[3] = hi ? a3  : rc1;
          acc[0] = __builtin_amdgcn_mfma_f32_32x32x16_f16(vf[0][ks], fu.h, acc[0], 0, 0, 0);
          acc[1] = __builtin_amdgcn_mfma_f32_32x32x16_f16(vf[1][ks], fu.h, acc[1], 0, 0, 0);
        }
      }

      __syncthreads();
      cur ^= 1;
    }

    const float inv = 1.0f / lrun;
    half_t* Orow = O + ((size_t)bb * SEQ + qg) * D_MODEL + hh * HDIM + hi * 4;
#pragma unroll
    for (int dt = 0; dt < 2; ++dt)
#pragma unroll
      for (int g = 0; g < 4; ++g) {
        half4 o;
#pragma unroll
        for (int jj = 0; jj < 4; ++jj) o[jj] = (_Float16)(acc[dt][g * 4 + jj] * inv);
        *(half4*)(Orow + dt * 32 + g * 8) = o;
      }
  }
}

// ---------------- GEMM2: out = AO @ w_out^T + b_out (fp32 out) ----------------
__global__ __launch_bounds__(256) void k_gemm_out(
    const half_t* __restrict__ A,
    const half_t* __restrict__ W,
    const float*  __restrict__ bias,
    float* __restrict__ C)
{
  constexpr int K = D_MODEL;
  __shared__ __align__(16) half_t As[2][BM * BK];
  __shared__ __align__(16) half_t Bs[2][BN * BK];
  const int tid  = threadIdx.x;
  const int wave = tid >> 6, lane = tid & 63;
  const int wr = wave >> 1, wc = wave & 1;
  const int lg = lane >> 4, lq = lane & 15;
  const int m0 = blockIdx.x * BM, n0 = blockIdx.y * BN;

  f32x4 acc[4][4] = {};
  const int srow = tid >> 2;
  const int scol = (tid & 3) * 8;

  const half_t* Ag = A + (size_t)(m0 + srow) * K + scol;
  const half_t* Wg = W + (size_t)(n0 + srow) * K + scol;
  const int wb = wave * 512;

  g2l16(Ag,                  &As[0][wb]);
  g2l16(Ag + (size_t)64 * K, &As[0][wb + 2048]);
  g2l16(Wg,                  &Bs[0][wb]);
  g2l16(Wg + (size_t)64 * K, &Bs[0][wb + 2048]);
  __syncthreads();

  int cur = 0;
  for (int k0 = 0; k0 < K; k0 += BK) {
    if (k0 + BK < K) {
      const int nb = cur ^ 1;
      g2l16(Ag + k0 + BK,                  &As[nb][wb]);
      g2l16(Ag + (size_t)64 * K + k0 + BK, &As[nb][wb + 2048]);
      g2l16(Wg + k0 + BK,                  &Bs[nb][wb]);
      g2l16(Wg + (size_t)64 * K + k0 + BK, &Bs[nb][wb + 2048]);
    }
    half8 af[4], bf[4];
#pragma unroll
    for (int mt = 0; mt < 4; ++mt)
      af[mt] = *(const half8*)(&As[cur][(wr * 64 + mt * 16 + lq) * BK + lg * 8]);
#pragma unroll
    for (int nt = 0; nt < 4; ++nt)
      bf[nt] = *(const half8*)(&Bs[cur][(wc * 64 + nt * 16 + lq) * BK + lg * 8]);
#pragma unroll
    for (int mt = 0; mt < 4; ++mt)
#pragma unroll
      for (int nt = 0; nt < 4; ++nt)
        acc[mt][nt] = __builtin_amdgcn_mfma_f32_16x16x32_f16(af[mt], bf[nt], acc[mt][nt], 0, 0, 0);
    __syncthreads();
    cur ^= 1;
  }

#pragma unroll
  for (int mt = 0; mt < 4; ++mt) {
#pragma unroll
    for (int nt = 0; nt < 4; ++nt) {
      const int n = n0 + wc * 64 + nt * 16 + lq;
      const float bv = bias[n];
#pragma unroll
      for (int r = 0; r < 4; ++r) {
        const int m = m0 + wr * 64 + mt * 16 + lg * 4 + r;
        C[(size_t)m * D_MODEL + n] = acc[mt][nt][r] + bv;
      }
    }
  }
}

// ---------------- launch ----------------
extern "C" void kernel_launch(void* const* d_in, const int* in_sizes, int n_in,
                              void* d_out, int out_size, void* d_ws, size_t ws_size,
                              hipStream_t stream) {
  const float* x    = (const float*)d_in[0];
  const float* wqkv = (const float*)d_in[1];
  const float* bqkv = (const float*)d_in[2];
  const float* wout = (const float*)d_in[3];
  const float* bout = (const float*)d_in[4];
  float* out = (float*)d_out;

  char* ws = (char*)d_ws;
  half_t* xb  = (half_t*)ws; ws += (size_t)MROWS * D_MODEL * 2;
  half_t* wqb = (half_t*)ws; ws += (size_t)3 * D_MODEL * D_MODEL * 2;
  half_t* wob = (half_t*)ws; ws += (size_t)D_MODEL * D_MODEL * 2;
  half_t* Qb  = (half_t*)ws; ws += (size_t)NBH * SEQ * HDIM * 2;
  half_t* Kb  = (half_t*)ws; ws += (size_t)NBH * SEQ * HDIM * 2;
  half_t* Vb  = (half_t*)ws; ws += (size_t)NBH * SEQ * HDIM * 2;
  half_t* AO  = (half_t*)ws; ws += (size_t)MROWS * D_MODEL * 2;

  k_cvt<<<MROWS * D_MODEL / 4 / 256, 256, 0, stream>>>(x, xb, MROWS * D_MODEL / 4);
  k_cvt<<<3 * D_MODEL * D_MODEL / 4 / 256, 256, 0, stream>>>(wqkv, wqb, 3 * D_MODEL * D_MODEL / 4);
  k_cvt<<<D_MODEL * D_MODEL / 4 / 256, 256, 0, stream>>>(wout, wob, D_MODEL * D_MODEL / 4);

  k_gemm_qkv<<<dim3(MROWS / BM, 3 * D_MODEL / BN), 256, 0, stream>>>(xb, wqb, bqkv, Qb, Kb, Vb);
  k_attn<<<dim3(512), 256, 0, stream>>>(Qb, Kb, Vb, AO);
  k_gemm_out<<<dim3(MROWS / BM, D_MODEL / BN), 256, 0, stream>>>(AO, wob, bout, out);
}